// Round 2
// baseline (416.698 us; speedup 1.0000x reference)
//
#include <hip/hip_runtime.h>
#include <hip/hip_bf16.h>
#include <stdint.h>

#define L_ 25
#define E_ 64
#define H_ 8
#define B_ 1000
#define S_ 512
#define GQ 2                       // batch elements per block (2 blocks/CU for barrier overlap)
#define NCELL (L_ * GQ)            // 50 cells per block
#define TPBR (NCELL * 8)           // 400 threads, thread = (cell, j)
#define NSUPER (S_ / 2 + L_ - 1)   // 280 supersteps (2 timesteps each)
#define HS 12                      // per-cell stride hsh/hrsh: 48B, banks disjoint
#define XG 20                      // per-cell stride xbuf: 80B, 2-way (free)

typedef float v2f __attribute__((ext_vector_type(2)));
typedef float v4f __attribute__((ext_vector_type(4)));

#define PIN(x) asm volatile("" : "+v"(x))

// v_pk_fma_f32: 2 fp32 FMAs per instruction (VOP3P)
__device__ __forceinline__ v2f pkfma(v2f a, v2f b, v2f c) {
  v2f d;
  asm("v_pk_fma_f32 %0, %1, %2, %3" : "=v"(d) : "v"(a), "v"(b), "v"(c));
  return d;
}
__device__ __forceinline__ v2f vlo(v4f v) { return __builtin_shufflevector(v, v, 0, 1); }
__device__ __forceinline__ v2f vhi(v4f v) { return __builtin_shufflevector(v, v, 2, 3); }
__device__ __forceinline__ v2f mk2(float a, float b) { v2f r; r.x = a; r.y = b; return r; }

__device__ __forceinline__ float ulo(uint32_t u) { return __uint_as_float(u << 16); }
__device__ __forceinline__ float uhi(uint32_t u) { return __uint_as_float(u & 0xffff0000u); }

__device__ __forceinline__ float toF(float v) { return v; }
__device__ __forceinline__ float toF(__hip_bfloat16 v) { return __bfloat162float(v); }
__device__ __forceinline__ void stP(float* p, float v) { *p = v; }
__device__ __forceinline__ void stP(__hip_bfloat16* p, float v) { *p = __float2bfloat16(v); }

__device__ __forceinline__ void load8f(const __hip_bfloat16* p, float* o) {
  const uint4 v = *(const uint4*)p;
  o[0] = ulo(v.x); o[1] = uhi(v.x); o[2] = ulo(v.y); o[3] = uhi(v.y);
  o[4] = ulo(v.z); o[5] = uhi(v.z); o[6] = ulo(v.w); o[7] = uhi(v.w);
}
__device__ __forceinline__ void load8f(const float* p, float* o) {
  const float4 a = ((const float4*)p)[0];
  const float4 b = ((const float4*)p)[1];
  o[0] = a.x; o[1] = a.y; o[2] = a.z; o[3] = a.w;
  o[4] = b.x; o[5] = b.y; o[6] = b.z; o[7] = b.w;
}

__device__ __forceinline__ void st4(float* p, float a, float b, float c, float d) {
  float4 v; v.x = a; v.y = b; v.z = c; v.w = d;
  *(float4*)p = v;
}
__device__ __forceinline__ void st4(__hip_bfloat16* p, float a, float b, float c, float d) {
  __hip_bfloat16 t[4] = {__float2bfloat16(a), __float2bfloat16(b),
                         __float2bfloat16(c), __float2bfloat16(d)};
  *(ushort4*)p = *(ushort4*)t;
}

// v_rcp_f32 (~1 ulp) instead of IEEE divide expansion.
__device__ __forceinline__ float sigmo(float x) {
  return __builtin_amdgcn_rcpf(1.f + __expf(-x));  // inf -> 0, large x -> 1: safe unclamped
}
// tanh(x) = 2*sigmoid(2x) - 1; inf-safe without clamp: exp(+inf)->inf, rcp(inf)->0 -> -1
__device__ __forceinline__ float tanh_(float x) {
  const float e = __expf(-2.f * x);
  return fmaf(2.f, __builtin_amdgcn_rcpf(1.f + e), -1.f);
}

// ---------------------------------------------------------------------------
// Kernel 0: dtype probe (fp32 vs bf16 inputs).
// ---------------------------------------------------------------------------
__global__ void gru_detect(const unsigned short* __restrict__ u16, int* __restrict__ flag) {
  const int i = threadIdx.x;  // 64 threads
  float m = 0.f;
#pragma unroll
  for (int k = 0; k < 4; ++k) {
    const uint32_t u = u16[i * 4 + k];
    float v = fabsf(__uint_as_float(u << 16));
    if (!(v < 1e30f)) v = 1e30f;
    m = fmaxf(m, v);
  }
#pragma unroll
  for (int off = 32; off; off >>= 1) m = fmaxf(m, __shfl_down(m, off, 64));
  if (i == 0) *flag = (m > 2.0f) ? 0 : 1;  // 0 = fp32 inputs, 1 = bf16 inputs
}

// ---------------------------------------------------------------------------
// Kernel 1: layer-0 x-projections. 1 token/thread, pk_fma compute, per-wave
// LDS transpose [24][65] (conflict-free) -> fully coalesced dwordx4 stores.
// pre[(b*S+t)*24 + gate*8 + j]. 2000 blocks x 256.
// ---------------------------------------------------------------------------
template <typename T, typename PT>
__global__ __launch_bounds__(256, 4) void gru_pre(
    const int* __restrict__ flag, int want,
    const int* __restrict__ x, const T* __restrict__ emb,
    const T* __restrict__ Wz, const T* __restrict__ Wr,
    const T* __restrict__ Wh, PT* __restrict__ pre) {
  if (*flag != want) return;
  __shared__ __align__(16) float WL[64 * 24];      // [k][z8 r8 h8], 6 KB
  __shared__ __align__(16) float TB[4][24 * 65];   // per-wave transpose, 24.4 KB
  for (int idx = threadIdx.x; idx < 64 * 24; idx += 256) {
    const int k = idx / 24, c = idx - k * 24;
    const T* src = (c < 8) ? Wz : ((c < 16) ? Wr : Wh);
    WL[idx] = toF(src[k * 8 + (c & 7)]);
  }
  __syncthreads();

  const int tok = blockIdx.x * 256 + threadIdx.x;
  const int t = x[tok];

  v2f acc[12];
#pragma unroll
  for (int q = 0; q < 12; ++q) acc[q] = mk2(0.f, 0.f);

  for (int kb = 0; kb < 8; ++kb) {
    float e[8];
    load8f(emb + (size_t)t * E_ + kb * 8, e);
#pragma unroll
    for (int k8 = 0; k8 < 8; ++k8) {
      const v4f* wr = (const v4f*)(WL + (kb * 8 + k8) * 24);  // broadcast b128
      const v2f ee = mk2(e[k8], e[k8]);
#pragma unroll
      for (int q = 0; q < 6; ++q) {
        const v4f w4 = wr[q];
        acc[2 * q]     = pkfma(ee, vlo(w4), acc[2 * q]);
        acc[2 * q + 1] = pkfma(ee, vhi(w4), acc[2 * q + 1]);
      }
    }
  }

  // in-wave transpose: write c-major (bank = (c+lane)%32, conflict-free)
  const int wid = threadIdx.x >> 6, lane = threadIdx.x & 63;
  float* tb = &TB[wid][0];
#pragma unroll
  for (int q = 0; q < 12; ++q) {
    tb[(2 * q) * 65 + lane] = acc[q].x;
    tb[(2 * q + 1) * 65 + lane] = acc[q].y;
  }
  asm volatile("s_waitcnt lgkmcnt(0)" ::: "memory");  // wave-local RAW through LDS
  __builtin_amdgcn_wave_barrier();

  // coalesced write-out: wave covers 64 tokens * 24 floats = 1536 floats
  PT* ob = pre + (size_t)(blockIdx.x * 256 + wid * 64) * 24;
#pragma unroll
  for (int it = 0; it < 6; ++it) {
    const int F0 = it * 256 + lane * 4;
    float o[4];
#pragma unroll
    for (int e2 = 0; e2 < 4; ++e2) {
      const int F = F0 + e2;
      const int tk = F / 24;          // magic-mul, unrolled
      const int c = F - tk * 24;
      o[e2] = tb[c * 65 + tk];
    }
    st4(ob + F0, o[0], o[1], o[2], o[3]);
  }
}

// ---------------------------------------------------------------------------
// Kernel 2: pipelined recurrence. Superstep s: layer l does t = 2(s-l), +1.
// GQ=2 -> 500 blocks x 400 threads, 2 blocks/CU: two async barrier groups
// cover each other's ds-round-trip + s_barrier stalls.
// Superstep is software-pipelined into 4 wave_barrier regions; independent
// work (both cells' x-projections, l==0 global prefetch) fills each ds
// round-trip window. A-cell h-chains use separate accumulators so they
// start as soon as the h b128s land (no dependence on the x-chain).
// ---------------------------------------------------------------------------
template <typename T, typename PT>
__global__ __launch_bounds__(TPBR, 4) void gru_rec(
    const int* __restrict__ flag, int want,
    const PT* __restrict__ pre,
    const T* __restrict__ Whz0, const T* __restrict__ bz0,
    const T* __restrict__ Whr0, const T* __restrict__ br0,
    const T* __restrict__ WrH0, const T* __restrict__ bH0,
    const T* __restrict__ Wxz, const T* __restrict__ Whz,
    const T* __restrict__ bz, const T* __restrict__ Wxr,
    const T* __restrict__ Whr, const T* __restrict__ br,
    const T* __restrict__ WxH, const T* __restrict__ WrH,
    const T* __restrict__ bH, const T* __restrict__ Why,
    const T* __restrict__ by, T* __restrict__ out) {
  if (*flag != want) return;
  __shared__ __align__(16) float hsh[NCELL * HS];
  __shared__ __align__(16) float hrsh[NCELL * HS];
  __shared__ __align__(16) float xbuf[2 * NCELL * XG];

  const int tid = threadIdx.x;
  const int gi = tid >> 3;   // cell = l*GQ + g, 0..NCELL-1
  const int j = tid & 7;
  const int l = gi >> 1;     // GQ=2
  const int g = gi & 1;
  const int b = blockIdx.x * GQ + g;

  for (int i = tid; i < NCELL * HS; i += TPBR) { hsh[i] = 0.f; hrsh[i] = 0.f; }
  for (int i = tid; i < 2 * NCELL * XG; i += TPBR) xbuf[i] = 0.f;  // l==0 x-reads are dead

  // ---- weight columns as packed (k,k+1) pairs, then PIN ----
  v2f wxz2[4], whz2[4], wxr2[4], whr2[4], wxh2[4], wrh2[4];
  v2f bz2, br2, bh2;  // {bias, 0}
  if (l == 0) {
#pragma unroll
    for (int q = 0; q < 4; ++q) {
      whz2[q] = mk2(toF(Whz0[(2 * q) * 8 + j]), toF(Whz0[(2 * q + 1) * 8 + j]));
      whr2[q] = mk2(toF(Whr0[(2 * q) * 8 + j]), toF(Whr0[(2 * q + 1) * 8 + j]));
      wrh2[q] = mk2(toF(WrH0[(2 * q) * 8 + j]), toF(WrH0[(2 * q + 1) * 8 + j]));
      wxz2[q] = mk2(0.f, 0.f); wxr2[q] = mk2(0.f, 0.f); wxh2[q] = mk2(0.f, 0.f);
    }
    bz2 = mk2(toF(bz0[j]), 0.f);
    br2 = mk2(toF(br0[j]), 0.f);
    bh2 = mk2(toF(bH0[j]), 0.f);
  } else {
    const int base = (l - 1) * 64;
#pragma unroll
    for (int q = 0; q < 4; ++q) {
      wxz2[q] = mk2(toF(Wxz[base + (2 * q) * 8 + j]), toF(Wxz[base + (2 * q + 1) * 8 + j]));
      whz2[q] = mk2(toF(Whz[base + (2 * q) * 8 + j]), toF(Whz[base + (2 * q + 1) * 8 + j]));
      wxr2[q] = mk2(toF(Wxr[base + (2 * q) * 8 + j]), toF(Wxr[base + (2 * q + 1) * 8 + j]));
      whr2[q] = mk2(toF(Whr[base + (2 * q) * 8 + j]), toF(Whr[base + (2 * q + 1) * 8 + j]));
      wxh2[q] = mk2(toF(WxH[base + (2 * q) * 8 + j]), toF(WxH[base + (2 * q + 1) * 8 + j]));
      wrh2[q] = mk2(toF(WrH[base + (2 * q) * 8 + j]), toF(WrH[base + (2 * q + 1) * 8 + j]));
    }
    bz2 = mk2(toF(bz[(l - 1) * 8 + j]), 0.f);
    br2 = mk2(toF(br[(l - 1) * 8 + j]), 0.f);
    bh2 = mk2(toF(bH[(l - 1) * 8 + j]), 0.f);
  }
#pragma unroll
  for (int q = 0; q < 4; ++q) {
    PIN(wxz2[q]); PIN(whz2[q]); PIN(wxr2[q]); PIN(whr2[q]); PIN(wxh2[q]); PIN(wrh2[q]);
  }
  PIN(bz2); PIN(br2); PIN(bh2);

  // layer-0 precomputed x-projection (register prefetch); 0 for l>0
  const PT* ppr = pre + (size_t)b * (S_ * 24) + j;
  float cz0 = 0.f, cr0 = 0.f, ch0 = 0.f, cz1 = 0.f, cr1 = 0.f, ch1 = 0.f;
  if (l == 0) {
    cz0 = toF(ppr[0]);  cr0 = toF(ppr[8]);  ch0 = toF(ppr[16]);
    cz1 = toF(ppr[24]); cr1 = toF(ppr[32]); ch1 = toF(ppr[40]);
  }

  float* hgw = hsh + gi * HS;
  float* hrg = hrsh + gi * HS;
  float* hgwj = hgw + j;
  float* hrgj = hrg + j;
  const int gp = (gi >= GQ) ? (gi - GQ) * XG : 0;
  const float* xpe = xbuf + NCELL * XG + gp;  // read when s even
  const float* xpo = xbuf + gp;               // read when s odd
  float* xce = xbuf + gi * XG;                // write when s even
  float* xco = xbuf + NCELL * XG + gi * XG;   // write when s odd

  float hown = 0.f;  // this thread's h[j], carried across supersteps

  __syncthreads();

  for (int s = 0; s < NSUPER; ++s) {
    const unsigned rel = (unsigned)(s - l);
    if (rel < (unsigned)(S_ / 2)) {
      const float* xp = (s & 1) ? xpo : xpe;
      float* xc = (s & 1) ? xco : xce;

      // ======== region 1: all loads; A h-chains + A,B x-chains; rA ========
      const v4f h01 = ((const v4f*)hgw)[0];   // h first: r-gate chain is critical
      const v4f h23 = ((const v4f*)hgw)[1];
      const v4f xa0 = ((const v4f*)xp)[0];
      const v4f xb0 = ((const v4f*)xp)[1];
      const v4f xa1 = ((const v4f*)xp)[2];
      const v4f xb1 = ((const v4f*)xp)[3];

      // l==0 global prefetch for next superstep, issued early (latency hidden)
      float pz0 = 0.f, pr0 = 0.f, ph0 = 0.f, pz1 = 0.f, pr1 = 0.f, ph1 = 0.f;
      const bool pf = (l == 0) && (rel + 1u < (unsigned)(S_ / 2));
      if (pf) {
        const PT* pn = ppr + (rel + 1) * 48;
        pz0 = toF(pn[0]);  pr0 = toF(pn[8]);  ph0 = toF(pn[16]);
        pz1 = toF(pn[24]); pr1 = toF(pn[32]); ph1 = toF(pn[40]);
      }

      // A h-part chains, separate accumulators (independent of x-chain)
      v2f arh = pkfma(vlo(h01), whr2[0], mk2(0.f, 0.f));
      arh = pkfma(vhi(h01), whr2[1], arh);
      arh = pkfma(vlo(h23), whr2[2], arh);
      arh = pkfma(vhi(h23), whr2[3], arh);
      v2f azh = pkfma(vlo(h01), whz2[0], mk2(0.f, 0.f));
      azh = pkfma(vhi(h01), whz2[1], azh);
      azh = pkfma(vlo(h23), whz2[2], azh);
      azh = pkfma(vhi(h23), whz2[3], azh);

      // A x-part chains
      v2f arp = pkfma(vlo(xa0), wxr2[0], br2);
      arp = pkfma(vhi(xa0), wxr2[1], arp);
      arp = pkfma(vlo(xb0), wxr2[2], arp);
      arp = pkfma(vhi(xb0), wxr2[3], arp);
      v2f azp = pkfma(vlo(xa0), wxz2[0], bz2);
      azp = pkfma(vhi(xa0), wxz2[1], azp);
      azp = pkfma(vlo(xb0), wxz2[2], azp);
      azp = pkfma(vhi(xb0), wxz2[3], azp);
      v2f ahp = pkfma(vlo(xa0), wxh2[0], bh2);
      ahp = pkfma(vhi(xa0), wxh2[1], ahp);
      ahp = pkfma(vlo(xb0), wxh2[2], ahp);
      ahp = pkfma(vhi(xb0), wxh2[3], ahp);

      // B x-part chains (fills A's latency slack)
      v2f arp1 = pkfma(vlo(xa1), wxr2[0], br2);
      arp1 = pkfma(vhi(xa1), wxr2[1], arp1);
      arp1 = pkfma(vlo(xb1), wxr2[2], arp1);
      arp1 = pkfma(vhi(xb1), wxr2[3], arp1);
      v2f azp1 = pkfma(vlo(xa1), wxz2[0], bz2);
      azp1 = pkfma(vhi(xa1), wxz2[1], azp1);
      azp1 = pkfma(vlo(xb1), wxz2[2], azp1);
      azp1 = pkfma(vhi(xb1), wxz2[3], azp1);
      v2f ahp1 = pkfma(vlo(xa1), wxh2[0], bh2);
      ahp1 = pkfma(vhi(xa1), wxh2[1], ahp1);
      ahp1 = pkfma(vlo(xb1), wxh2[2], ahp1);
      ahp1 = pkfma(vhi(xb1), wxh2[3], ahp1);

      const float ar0 = (arp.x + arp.y) + (arh.x + arh.y) + cr0;
      const float rA = sigmo(ar0);
      *hrgj = hown * rA;
      __builtin_amdgcn_wave_barrier();

      // ======== region 2: read hr_A; zA + wrh + tanh; write h_A ========
      const v4f r01 = ((const v4f*)hrg)[0];
      const v4f r23 = ((const v4f*)hrg)[1];
      const float az0 = (azp.x + azp.y) + (azh.x + azh.y) + cz0;
      const float zA = sigmo(az0);
      ahp = pkfma(vlo(r01), wrh2[0], ahp);
      ahp = pkfma(vhi(r01), wrh2[1], ahp);
      ahp = pkfma(vlo(r23), wrh2[2], ahp);
      ahp = pkfma(vhi(r23), wrh2[3], ahp);
      const float ah0 = ahp.x + ahp.y + ch0;
      const float hn0 = fmaf(zA, tanh_(ah0) - hown, hown);
      *hgwj = hn0;
      xc[j] = hn0;  // publish timestep A for layer l+1
      __builtin_amdgcn_wave_barrier();

      // ======== region 3: read h_A; B h-parts; rB ========
      const v4f g01 = ((const v4f*)hgw)[0];
      const v4f g23 = ((const v4f*)hgw)[1];
      arp1 = pkfma(vlo(g01), whr2[0], arp1);
      arp1 = pkfma(vhi(g01), whr2[1], arp1);
      arp1 = pkfma(vlo(g23), whr2[2], arp1);
      arp1 = pkfma(vhi(g23), whr2[3], arp1);
      azp1 = pkfma(vlo(g01), whz2[0], azp1);
      azp1 = pkfma(vhi(g01), whz2[1], azp1);
      azp1 = pkfma(vlo(g23), whz2[2], azp1);
      azp1 = pkfma(vhi(g23), whz2[3], azp1);
      const float ar1 = arp1.x + arp1.y + cr1;
      const float rB = sigmo(ar1);
      *hrgj = hn0 * rB;
      __builtin_amdgcn_wave_barrier();

      // ======== region 4: read hr_B; zB + wrh + tanh; write h_B ========
      const v4f q01 = ((const v4f*)hrg)[0];
      const v4f q23 = ((const v4f*)hrg)[1];
      const float az1 = azp1.x + azp1.y + cz1;
      const float zB = sigmo(az1);
      ahp1 = pkfma(vlo(q01), wrh2[0], ahp1);
      ahp1 = pkfma(vhi(q01), wrh2[1], ahp1);
      ahp1 = pkfma(vlo(q23), wrh2[2], ahp1);
      ahp1 = pkfma(vhi(q23), wrh2[3], ahp1);
      const float ah1 = ahp1.x + ahp1.y + ch1;
      const float hn1 = fmaf(zB, tanh_(ah1) - hn0, hn0);
      *hgwj = hn1;
      xc[8 + j] = hn1;  // publish timestep B for layer l+1
      hown = hn1;
      if (pf) { cz0 = pz0; cr0 = pr0; ch0 = ph0; cz1 = pz1; cr1 = pr1; ch1 = ph1; }
    }
    __syncthreads();  // full fence: orders xbuf/hsh across waves for next superstep
  }

  // ---- epilogue ----
  stP(out + B_ + (l * B_ + b) * H_ + j, hown);
  if (l == L_ - 1 && j == 0) {
    float ssum = toF(by[0]);
#pragma unroll
    for (int k = 0; k < 8; ++k) ssum = fmaf(hgw[k], toF(Why[k]), ssum);
    stP(out + b, ssum);
  }
}

// ---------------------------------------------------------------------------
template <typename T, typename PT>
static void launch_mode(const int* flag, int want, void* const* d_in, PT* pre,
                        T* out, hipStream_t stream) {
  const int* x = (const int*)d_in[0];
  const T* emb = (const T*)d_in[1];
  const T* Wxz0 = (const T*)d_in[2];
  const T* Whz0 = (const T*)d_in[3];
  const T* bz0 = (const T*)d_in[4];
  const T* Wxr0 = (const T*)d_in[5];
  const T* Whr0 = (const T*)d_in[6];
  const T* br0 = (const T*)d_in[7];
  const T* WxH0 = (const T*)d_in[8];
  const T* WrH0 = (const T*)d_in[9];
  const T* bH0 = (const T*)d_in[10];
  const T* Wxz = (const T*)d_in[11];
  const T* Whz = (const T*)d_in[12];
  const T* bz = (const T*)d_in[13];
  const T* Wxr = (const T*)d_in[14];
  const T* Whr = (const T*)d_in[15];
  const T* br = (const T*)d_in[16];
  const T* WxH = (const T*)d_in[17];
  const T* WrH = (const T*)d_in[18];
  const T* bH = (const T*)d_in[19];
  const T* Why = (const T*)d_in[20];
  const T* by = (const T*)d_in[21];

  gru_pre<T, PT><<<B_ * S_ / 256, 256, 0, stream>>>(flag, want, x, emb,
                                                    Wxz0, Wxr0, WxH0, pre);
  gru_rec<T, PT><<<B_ / GQ, TPBR, 0, stream>>>(
      flag, want, pre, Whz0, bz0, Whr0, br0, WrH0, bH0, Wxz, Whz, bz, Wxr, Whr,
      br, WxH, WrH, bH, Why, by, out);
}

extern "C" void kernel_launch(void* const* d_in, const int* in_sizes, int n_in,
                              void* d_out, int out_size, void* d_ws, size_t ws_size,
                              hipStream_t stream) {
  int* flag = (int*)d_ws;
  char* preMem = (char*)d_ws + 256;
  const size_t needF = (size_t)B_ * S_ * 24 * sizeof(float) + 256;

  gru_detect<<<1, 64, 0, stream>>>((const unsigned short*)d_in[1], flag);

  if (ws_size >= needF) {
    float* pre = (float*)preMem;
    launch_mode<float, float>(flag, 0, d_in, pre, (float*)d_out, stream);
    launch_mode<__hip_bfloat16, float>(flag, 1, d_in, pre, (__hip_bfloat16*)d_out, stream);
  } else {
    __hip_bfloat16* pre = (__hip_bfloat16*)preMem;
    launch_mode<float, __hip_bfloat16>(flag, 0, d_in, pre, (float*)d_out, stream);
    launch_mode<__hip_bfloat16, __hip_bfloat16>(flag, 1, d_in, pre, (__hip_bfloat16*)d_out, stream);
  }
}

// Round 3
// 408.718 us; speedup vs baseline: 1.0195x; 1.0195x over previous
//
#include <hip/hip_runtime.h>
#include <hip/hip_bf16.h>
#include <stdint.h>

#define L_ 25
#define E_ 64
#define H_ 8
#define B_ 1000
#define S_ 512
#define GQ 4                       // batch elements per block (GQ=4 measured faster than 2)
#define NCELL (L_ * GQ)            // 100 cells per block
#define TPBR (NCELL * 8)           // 800 threads, thread = (cell, j)
#define NSUPER (S_ / 2 + L_ - 1)   // 280 supersteps (2 timesteps each)
#define HS 12                      // per-cell stride hsh/hrsh: 48B, banks disjoint
#define XG 20                      // per-cell stride xbuf: 80B, 2-way (free)

typedef float v2f __attribute__((ext_vector_type(2)));
typedef float v4f __attribute__((ext_vector_type(4)));

#define PIN(x) asm volatile("" : "+v"(x))

// v_pk_fma_f32: {a.x*b.x+c.x, a.y*b.y+c.y}
__device__ __forceinline__ v2f pkfma(v2f a, v2f b, v2f c) {
  v2f d;
  asm("v_pk_fma_f32 %0, %1, %2, %3" : "=v"(d) : "v"(a), "v"(b), "v"(c));
  return d;
}
// op_sel broadcast of a.x: {a.x*b.x+c.x, a.x*b.y+c.y}
__device__ __forceinline__ v2f pkfma_l(v2f a, v2f b, v2f c) {
  v2f d;
  asm("v_pk_fma_f32 %0, %1, %2, %3 op_sel:[0,0,0] op_sel_hi:[0,1,1]"
      : "=v"(d) : "v"(a), "v"(b), "v"(c));
  return d;
}
// op_sel broadcast of a.y: {a.y*b.x+c.x, a.y*b.y+c.y}
__device__ __forceinline__ v2f pkfma_h(v2f a, v2f b, v2f c) {
  v2f d;
  asm("v_pk_fma_f32 %0, %1, %2, %3 op_sel:[1,0,0] op_sel_hi:[1,1,1]"
      : "=v"(d) : "v"(a), "v"(b), "v"(c));
  return d;
}
__device__ __forceinline__ v2f pkadd(v2f a, v2f b) {
  v2f d;
  asm("v_pk_add_f32 %0, %1, %2" : "=v"(d) : "v"(a), "v"(b));
  return d;
}
__device__ __forceinline__ v2f vlo(v4f v) { return __builtin_shufflevector(v, v, 0, 1); }
__device__ __forceinline__ v2f vhi(v4f v) { return __builtin_shufflevector(v, v, 2, 3); }
__device__ __forceinline__ v2f mk2(float a, float b) { v2f r; r.x = a; r.y = b; return r; }

// 8-long k-chain: acc.{x,y} += sum_k m[k] * w[k].{x,y}; m given as two v4f
#define CHAIN8(acc, ma, mb, w)            \
  acc = pkfma_l(vlo(ma), w[0], acc);      \
  acc = pkfma_h(vlo(ma), w[1], acc);      \
  acc = pkfma_l(vhi(ma), w[2], acc);      \
  acc = pkfma_h(vhi(ma), w[3], acc);      \
  acc = pkfma_l(vlo(mb), w[4], acc);      \
  acc = pkfma_h(vlo(mb), w[5], acc);      \
  acc = pkfma_l(vhi(mb), w[6], acc);      \
  acc = pkfma_h(vhi(mb), w[7], acc);

// 4-long paired chain: acc += {m[2q]*w[q].x, m[2q+1]*w[q].y}; hadd at consume
#define CHAIN4P(acc, ma, mb, w)           \
  acc = pkfma(vlo(ma), w[0], acc);        \
  acc = pkfma(vhi(ma), w[1], acc);        \
  acc = pkfma(vlo(mb), w[2], acc);        \
  acc = pkfma(vhi(mb), w[3], acc);

__device__ __forceinline__ float ulo(uint32_t u) { return __uint_as_float(u << 16); }
__device__ __forceinline__ float uhi(uint32_t u) { return __uint_as_float(u & 0xffff0000u); }

__device__ __forceinline__ float toF(float v) { return v; }
__device__ __forceinline__ float toF(__hip_bfloat16 v) { return __bfloat162float(v); }
__device__ __forceinline__ void stP(float* p, float v) { *p = v; }
__device__ __forceinline__ void stP(__hip_bfloat16* p, float v) { *p = __float2bfloat16(v); }

__device__ __forceinline__ v2f loadC2(const float* p) { return *(const v2f*)p; }
__device__ __forceinline__ v2f loadC2(const __hip_bfloat16* p) {
  const uint32_t u = *(const uint32_t*)p;
  return mk2(ulo(u), uhi(u));
}

__device__ __forceinline__ void load8f(const __hip_bfloat16* p, float* o) {
  const uint4 v = *(const uint4*)p;
  o[0] = ulo(v.x); o[1] = uhi(v.x); o[2] = ulo(v.y); o[3] = uhi(v.y);
  o[4] = ulo(v.z); o[5] = uhi(v.z); o[6] = ulo(v.w); o[7] = uhi(v.w);
}
__device__ __forceinline__ void load8f(const float* p, float* o) {
  const float4 a = ((const float4*)p)[0];
  const float4 b = ((const float4*)p)[1];
  o[0] = a.x; o[1] = a.y; o[2] = a.z; o[3] = a.w;
  o[4] = b.x; o[5] = b.y; o[6] = b.z; o[7] = b.w;
}

__device__ __forceinline__ void st4(float* p, float a, float b, float c, float d) {
  float4 v; v.x = a; v.y = b; v.z = c; v.w = d;
  *(float4*)p = v;
}
__device__ __forceinline__ void st4(__hip_bfloat16* p, float a, float b, float c, float d) {
  __hip_bfloat16 t[4] = {__float2bfloat16(a), __float2bfloat16(b),
                         __float2bfloat16(c), __float2bfloat16(d)};
  *(ushort4*)p = *(ushort4*)t;
}

// v_rcp_f32 (~1 ulp) instead of IEEE divide expansion.
__device__ __forceinline__ float sigmo(float x) {
  return __builtin_amdgcn_rcpf(1.f + __expf(-x));
}
__device__ __forceinline__ float tanh_(float x) {
  const float e = __expf(-2.f * x);
  return fmaf(2.f, __builtin_amdgcn_rcpf(1.f + e), -1.f);
}

// Per-block dtype probe (replaces the separate gru_detect kernel): max of the
// first 256 shorts of emb interpreted as bf16. fp32 data has random exponent
// bits in its mantissa-halves -> max >> 2; bf16 N(0,0.1) data -> max < 2.
__device__ __forceinline__ void detect64(const unsigned short* __restrict__ u,
                                         int tid, float* fl) {
  if (tid < 64) {
    float m = 0.f;
#pragma unroll
    for (int k = 0; k < 4; ++k) {
      const uint32_t q = u[tid * 4 + k];
      float v = fabsf(__uint_as_float(q << 16));
      if (!(v < 1e30f)) v = 1e30f;
      m = fmaxf(m, v);
    }
#pragma unroll
    for (int off = 32; off; off >>= 1) m = fmaxf(m, __shfl_down(m, off, 64));
    if (tid == 0) *fl = (m > 2.0f) ? 0.f : 1.f;
  }
}

// ---------------------------------------------------------------------------
// Kernel 1 body: layer-0 x-projections. pre token layout (24 floats):
// [2j]={z_j}, [2j+1]={r_j} (interleaved pairs), [16+j]={h_j}.
// ---------------------------------------------------------------------------
template <typename T, typename PT>
__device__ __forceinline__ void pre_body(
    const int* __restrict__ x, const void* __restrict__ embv,
    const void* __restrict__ Wzv, const void* __restrict__ Wrv,
    const void* __restrict__ Whv, PT* __restrict__ pre,
    float* WL, float* TBb) {
  const T* emb = (const T*)embv;
  const T* Wz = (const T*)Wzv;
  const T* Wr = (const T*)Wrv;
  const T* Wh = (const T*)Whv;
  const int tid = threadIdx.x;

  for (int idx = tid; idx < 64 * 24; idx += 256) {
    const int k = idx / 24, c = idx - k * 24;
    float w;
    if (c < 16) w = toF(((c & 1) ? Wr : Wz)[k * 8 + (c >> 1)]);
    else        w = toF(Wh[k * 8 + (c - 16)]);
    WL[idx] = w;
  }
  __syncthreads();

  const int tok = blockIdx.x * 256 + tid;
  const int t = x[tok];

  v2f acc[12];
#pragma unroll
  for (int q = 0; q < 12; ++q) acc[q] = mk2(0.f, 0.f);

  for (int kb = 0; kb < 8; ++kb) {
    float e[8];
    load8f(emb + (size_t)t * E_ + kb * 8, e);
#pragma unroll
    for (int k8 = 0; k8 < 8; ++k8) {
      const v4f* wr = (const v4f*)(WL + (kb * 8 + k8) * 24);
      const v2f ee = mk2(e[k8], e[k8]);
#pragma unroll
      for (int q = 0; q < 6; ++q) {
        const v4f w4 = wr[q];
        acc[2 * q]     = pkfma(ee, vlo(w4), acc[2 * q]);
        acc[2 * q + 1] = pkfma(ee, vhi(w4), acc[2 * q + 1]);
      }
    }
  }

  // in-wave transpose: [24][65] per wave, conflict-free
  const int wid = tid >> 6, lane = tid & 63;
  float* tb = TBb + wid * (24 * 65);
#pragma unroll
  for (int q = 0; q < 12; ++q) {
    tb[(2 * q) * 65 + lane] = acc[q].x;
    tb[(2 * q + 1) * 65 + lane] = acc[q].y;
  }
  asm volatile("s_waitcnt lgkmcnt(0)" ::: "memory");
  __builtin_amdgcn_wave_barrier();

  // coalesced write-out: wave covers 64 tokens * 24 floats
  PT* ob = pre + (size_t)(blockIdx.x * 256 + wid * 64) * 24;
#pragma unroll
  for (int it = 0; it < 6; ++it) {
    const int F0 = it * 256 + lane * 4;
    float o[4];
#pragma unroll
    for (int e2 = 0; e2 < 4; ++e2) {
      const int F = F0 + e2;
      const int tk = F / 24;
      const int c = F - tk * 24;
      o[e2] = tb[c * 65 + tk];
    }
    st4(ob + F0, o[0], o[1], o[2], o[3]);
  }
}

template <typename PT>
__global__ __launch_bounds__(256, 4) void gru_pre(
    const int* __restrict__ x, const void* __restrict__ emb,
    const void* __restrict__ Wz, const void* __restrict__ Wr,
    const void* __restrict__ Wh, PT* __restrict__ pre) {
  __shared__ __align__(16) float WL[64 * 24];      // 6 KB
  __shared__ __align__(16) float TB[4][24 * 65];   // 24.4 KB
  __shared__ float fl;
  detect64((const unsigned short*)emb, threadIdx.x, &fl);
  __syncthreads();
  if (fl != 0.f) pre_body<__hip_bfloat16, PT>(x, emb, Wz, Wr, Wh, pre, WL, &TB[0][0]);
  else           pre_body<float, PT>(x, emb, Wz, Wr, Wh, pre, WL, &TB[0][0]);
}

// ---------------------------------------------------------------------------
// Kernel 2 body: pipelined recurrence. Superstep s: layer l does t=2(s-l),+1.
// z,r gates packed in one v2f via op_sel pkfma (no horizontal-add tails);
// weights pinned in VGPRs; 4 wave_barrier regions per superstep.
// ---------------------------------------------------------------------------
template <typename T, typename PT>
__device__ __forceinline__ void rec_body(
    const PT* __restrict__ pre,
    const void* __restrict__ Whz0v, const void* __restrict__ bz0v,
    const void* __restrict__ Whr0v, const void* __restrict__ br0v,
    const void* __restrict__ WrH0v, const void* __restrict__ bH0v,
    const void* __restrict__ Wxzv, const void* __restrict__ Whzv,
    const void* __restrict__ bzv, const void* __restrict__ Wxrv,
    const void* __restrict__ Whrv, const void* __restrict__ brv,
    const void* __restrict__ WxHv, const void* __restrict__ WrHv,
    const void* __restrict__ bHv, const void* __restrict__ Whyv,
    const void* __restrict__ byv, void* __restrict__ outv,
    float* hsh, float* hrsh, float* xbuf) {
  const T* Whz0 = (const T*)Whz0v; const T* bz0 = (const T*)bz0v;
  const T* Whr0 = (const T*)Whr0v; const T* br0 = (const T*)br0v;
  const T* WrH0 = (const T*)WrH0v; const T* bH0 = (const T*)bH0v;
  const T* Wxz = (const T*)Wxzv;   const T* Whz = (const T*)Whzv;
  const T* bz = (const T*)bzv;     const T* Wxr = (const T*)Wxrv;
  const T* Whr = (const T*)Whrv;   const T* br = (const T*)brv;
  const T* WxH = (const T*)WxHv;   const T* WrH = (const T*)WrHv;
  const T* bH = (const T*)bHv;     const T* Why = (const T*)Whyv;
  const T* by = (const T*)byv;     T* out = (T*)outv;

  const int tid = threadIdx.x;
  const int gi = tid >> 3;   // cell = l*GQ + g
  const int j = tid & 7;
  const int l = gi >> 2;     // GQ=4
  const int g = gi & 3;
  const int b = blockIdx.x * GQ + g;

  for (int i = tid; i < NCELL * HS; i += TPBR) { hsh[i] = 0.f; hrsh[i] = 0.f; }
  for (int i = tid; i < 2 * NCELL * XG; i += TPBR) xbuf[i] = 0.f;  // l==0 x-reads dead

  // ---- weights: z,r packed as {Wz[k][j], Wr[k][j]}; H-gate k-paired ----
  v2f wzrx[8], wzrh[8], wxh2[4], wrh2[4], bzr;
  float vbh;
  if (l == 0) {
#pragma unroll
    for (int k = 0; k < 8; ++k) {
      wzrh[k] = mk2(toF(Whz0[k * 8 + j]), toF(Whr0[k * 8 + j]));
      wzrx[k] = mk2(0.f, 0.f);
    }
#pragma unroll
    for (int q = 0; q < 4; ++q) {
      wrh2[q] = mk2(toF(WrH0[(2 * q) * 8 + j]), toF(WrH0[(2 * q + 1) * 8 + j]));
      wxh2[q] = mk2(0.f, 0.f);
    }
    bzr = mk2(toF(bz0[j]), toF(br0[j]));
    vbh = toF(bH0[j]);
  } else {
    const int base = (l - 1) * 64;
#pragma unroll
    for (int k = 0; k < 8; ++k) {
      wzrx[k] = mk2(toF(Wxz[base + k * 8 + j]), toF(Wxr[base + k * 8 + j]));
      wzrh[k] = mk2(toF(Whz[base + k * 8 + j]), toF(Whr[base + k * 8 + j]));
    }
#pragma unroll
    for (int q = 0; q < 4; ++q) {
      wxh2[q] = mk2(toF(WxH[base + (2 * q) * 8 + j]), toF(WxH[base + (2 * q + 1) * 8 + j]));
      wrh2[q] = mk2(toF(WrH[base + (2 * q) * 8 + j]), toF(WrH[base + (2 * q + 1) * 8 + j]));
    }
    bzr = mk2(toF(bz[(l - 1) * 8 + j]), toF(br[(l - 1) * 8 + j]));
    vbh = toF(bH[(l - 1) * 8 + j]);
  }
#pragma unroll
  for (int k = 0; k < 8; ++k) { PIN(wzrx[k]); PIN(wzrh[k]); }
#pragma unroll
  for (int q = 0; q < 4; ++q) { PIN(wxh2[q]); PIN(wrh2[q]); }
  PIN(bzr); PIN(vbh);

  // layer-0 precomputed x-projection; {z,r} as one v2f, h scalar
  const PT* ppr = pre + (size_t)b * (S_ * 24);
  v2f czrA = mk2(0.f, 0.f), czrB = mk2(0.f, 0.f);
  float chA = 0.f, chB = 0.f;
  if (l == 0) {
    czrA = loadC2(ppr + 2 * j);      chA = toF(ppr[16 + j]);
    czrB = loadC2(ppr + 24 + 2 * j); chB = toF(ppr[24 + 16 + j]);
  }

  float* hgw = hsh + gi * HS;
  float* hrg = hrsh + gi * HS;
  float* hgwj = hgw + j;
  float* hrgj = hrg + j;
  const int gp = (gi >= GQ) ? (gi - GQ) * XG : 0;
  const float* xpe = xbuf + NCELL * XG + gp;  // read when s even
  const float* xpo = xbuf + gp;               // read when s odd
  float* xce = xbuf + gi * XG;                // write when s even
  float* xco = xbuf + NCELL * XG + gi * XG;   // write when s odd

  float hown = 0.f;

  __syncthreads();

  for (int s = 0; s < NSUPER; ++s) {
    const unsigned rel = (unsigned)(s - l);
    if (rel < (unsigned)(S_ / 2)) {
      const float* xp = (s & 1) ? xpo : xpe;
      float* xc = (s & 1) ? xco : xce;

      // ======== region 1: loads; A h/x chains + B x chains; rA ========
      const v4f h01 = ((const v4f*)hgw)[0];
      const v4f h23 = ((const v4f*)hgw)[1];
      const v4f xa0 = ((const v4f*)xp)[0];
      const v4f xb0 = ((const v4f*)xp)[1];
      const v4f xa1 = ((const v4f*)xp)[2];
      const v4f xb1 = ((const v4f*)xp)[3];

      // l==0 global prefetch for next superstep (latency hidden under compute)
      v2f nzrA = mk2(0.f, 0.f), nzrB = mk2(0.f, 0.f);
      float nhA = 0.f, nhB = 0.f;
      const bool pf = (l == 0) && (rel + 1u < (unsigned)(S_ / 2));
      if (pf) {
        const PT* pn = ppr + (2 * rel + 2) * 24;
        nzrA = loadC2(pn + 2 * j);      nhA = toF(pn[16 + j]);
        nzrB = loadC2(pn + 24 + 2 * j); nhB = toF(pn[24 + 16 + j]);
      }

      v2f azrh = bzr;               // {z,r} h-part
      CHAIN8(azrh, h01, h23, wzrh);
      v2f azrxA = czrA;             // {z,r} x-part, cell A
      CHAIN8(azrxA, xa0, xb0, wzrx);
      v2f ahA = mk2(chA, vbh);      // H-gate x-part, cell A (hadd at consume)
      CHAIN4P(ahA, xa0, xb0, wxh2);
      v2f azrxB = czrB;             // {z,r} x-part, cell B
      CHAIN8(azrxB, xa1, xb1, wzrx);
      v2f ahB = mk2(chB, vbh);      // H-gate x-part, cell B
      CHAIN4P(ahB, xa1, xb1, wxh2);

      const v2f azrA = pkadd(azrh, azrxA);
      const float rA = sigmo(azrA.y);
      *hrgj = hown * rA;
      __builtin_amdgcn_wave_barrier();

      // ======== region 2: read hr_A; zA; H-gate; write h_A ========
      const v4f r01 = ((const v4f*)hrg)[0];
      const v4f r23 = ((const v4f*)hrg)[1];
      const float zA = sigmo(azrA.x);
      CHAIN4P(ahA, r01, r23, wrh2);
      const float hcA = tanh_(ahA.x + ahA.y);
      const float hn0 = fmaf(zA, hcA - hown, hown);
      *hgwj = hn0;
      xc[j] = hn0;
      __builtin_amdgcn_wave_barrier();

      // ======== region 3: read h_A; B h chains; rB ========
      const v4f g01 = ((const v4f*)hgw)[0];
      const v4f g23 = ((const v4f*)hgw)[1];
      v2f azrhB = bzr;
      CHAIN8(azrhB, g01, g23, wzrh);
      const v2f azrB = pkadd(azrhB, azrxB);
      const float rB = sigmo(azrB.y);
      *hrgj = hn0 * rB;
      __builtin_amdgcn_wave_barrier();

      // ======== region 4: read hr_B; zB; H-gate; write h_B ========
      const v4f q01 = ((const v4f*)hrg)[0];
      const v4f q23 = ((const v4f*)hrg)[1];
      const float zB = sigmo(azrB.x);
      CHAIN4P(ahB, q01, q23, wrh2);
      const float hcB = tanh_(ahB.x + ahB.y);
      const float hn1 = fmaf(zB, hcB - hn0, hn0);
      *hgwj = hn1;
      xc[8 + j] = hn1;
      hown = hn1;
      czrA = nzrA; chA = nhA; czrB = nzrB; chB = nhB;
    }
    __syncthreads();
  }

  // ---- epilogue ----
  stP(out + B_ + (l * B_ + b) * H_ + j, hown);
  if (l == L_ - 1 && j == 0) {
    float ssum = toF(by[0]);
#pragma unroll
    for (int k = 0; k < 8; ++k) ssum = fmaf(hgw[k], toF(Why[k]), ssum);
    stP(out + b, ssum);
  }
}

template <typename PT>
__global__ __launch_bounds__(TPBR, 4) void gru_rec(
    const void* __restrict__ emb, const PT* __restrict__ pre,
    const void* __restrict__ Whz0, const void* __restrict__ bz0,
    const void* __restrict__ Whr0, const void* __restrict__ br0,
    const void* __restrict__ WrH0, const void* __restrict__ bH0,
    const void* __restrict__ Wxz, const void* __restrict__ Whz,
    const void* __restrict__ bz, const void* __restrict__ Wxr,
    const void* __restrict__ Whr, const void* __restrict__ br,
    const void* __restrict__ WxH, const void* __restrict__ WrH,
    const void* __restrict__ bH, const void* __restrict__ Why,
    const void* __restrict__ by, void* __restrict__ out) {
  __shared__ __align__(16) float hsh[NCELL * HS];
  __shared__ __align__(16) float hrsh[NCELL * HS];
  __shared__ __align__(16) float xbuf[2 * NCELL * XG];
  __shared__ float fl;
  detect64((const unsigned short*)emb, threadIdx.x, &fl);
  __syncthreads();
  if (fl != 0.f)
    rec_body<__hip_bfloat16, PT>(pre, Whz0, bz0, Whr0, br0, WrH0, bH0, Wxz, Whz,
                                 bz, Wxr, Whr, br, WxH, WrH, bH, Why, by, out,
                                 hsh, hrsh, xbuf);
  else
    rec_body<float, PT>(pre, Whz0, bz0, Whr0, br0, WrH0, bH0, Wxz, Whz, bz, Wxr,
                        Whr, br, WxH, WrH, bH, Why, by, out, hsh, hrsh, xbuf);
}

// ---------------------------------------------------------------------------
template <typename PT>
static void launch_all(void* const* d_in, PT* pre, void* d_out, hipStream_t stream) {
  gru_pre<PT><<<B_ * S_ / 256, 256, 0, stream>>>(
      (const int*)d_in[0], d_in[1], d_in[2], d_in[5], d_in[8], pre);
  gru_rec<PT><<<B_ / GQ, TPBR, 0, stream>>>(
      d_in[1], pre, d_in[3], d_in[4], d_in[6], d_in[7], d_in[9], d_in[10],
      d_in[11], d_in[12], d_in[13], d_in[14], d_in[15], d_in[16], d_in[17],
      d_in[18], d_in[19], d_in[20], d_in[21], d_out);
}

extern "C" void kernel_launch(void* const* d_in, const int* in_sizes, int n_in,
                              void* d_out, int out_size, void* d_ws, size_t ws_size,
                              hipStream_t stream) {
  const size_t needF = (size_t)B_ * S_ * 24 * sizeof(float);
  if (ws_size >= needF)
    launch_all<float>(d_in, (float*)d_ws, d_out, stream);
  else
    launch_all<__hip_bfloat16>(d_in, (__hip_bfloat16*)d_ws, d_out, stream);
}